// Round 18
// baseline (155.684 us; speedup 1.0000x reference)
//
#include <hip/hip_runtime.h>
#include <hip/hip_bf16.h>
#include <stdint.h>

typedef short v8s __attribute__((ext_vector_type(8)));
typedef float v4f __attribute__((ext_vector_type(4)));
typedef unsigned long long u64;
typedef unsigned short u16;
typedef unsigned int u32;
typedef u64 v2u __attribute__((ext_vector_type(2)));

// ---------- helpers ----------
__device__ __forceinline__ u16 f2bf(float f) {
    unsigned u = __builtin_bit_cast(unsigned, f);
    u += 0x7FFFu + ((u >> 16) & 1u);   // RNE
    return (u16)(u >> 16);
}

__device__ __forceinline__ u32 cvt_pk_bf16(float lo, float hi) {
    u32 r;
    asm("v_cvt_pk_bf16_f32 %0, %1, %2" : "=v"(r) : "v"(lo), "v"(hi));
    return r;
}

__device__ __forceinline__ float ex2(float x) {   // 2^x
    float r;
    asm("v_exp_f32 %0, %1" : "=v"(r) : "v"(x));
    return r;
}

__device__ __forceinline__ void gload_lds16(const void* g, const void* lds) {
    __builtin_amdgcn_global_load_lds(
        (const __attribute__((address_space(1))) unsigned int*)(unsigned long long)g,
        (__attribute__((address_space(3))) unsigned int*)(unsigned int)(unsigned long long)lds,
        16, 0, 0);
}

// ---------- fused fp32 -> bf16 conversion (x, Wq, Wk, Wv in one launch) ----------
__global__ __launch_bounds__(256) void cvt_all(const float* __restrict__ x,
                                               const float* __restrict__ wq,
                                               const float* __restrict__ wk,
                                               const float* __restrict__ wv,
                                               u16* __restrict__ xb, u16* __restrict__ wqb,
                                               u16* __restrict__ wkb, u16* __restrict__ wvb) {
    int i = blockIdx.x * 256 + threadIdx.x;   // v4 index over concatenated regions
    const float* in;
    u16* out;
    if (i < 2097152)      { in = x;  out = xb; }
    else if (i < 2359296) { in = wq; out = wqb; i -= 2097152; }
    else if (i < 2621440) { in = wk; out = wkb; i -= 2359296; }
    else                  { in = wv; out = wvb; i -= 2621440; }
    float4 v = ((const float4*)in)[i];
    ((ushort4*)out)[i] = make_ushort4(f2bf(v.x), f2bf(v.y), f2bf(v.z), f2bf(v.w));
}

// ---------- merged QKV projection GEMM (m97 structure + T2 swizzle + T1 XCD swizzle) ----------
// C[m][n] = sum_k X[m][k] * W[n][k] + bias[n]
// mode 0: Q -> [bh][s][d] bf16, scaled by 0.125*log2(e)
// mode 1: K -> [bh][s][d] bf16
// mode 2: V -> V^T [bh][d][s] bf16 (transposed via LDS)
__global__ __launch_bounds__(256, 4)
void qkv_gemm_all(const u16* __restrict__ X,
                  const u16* __restrict__ Wq, const u16* __restrict__ Wk, const u16* __restrict__ Wv,
                  const float* __restrict__ bq, const float* __restrict__ bk, const float* __restrict__ bv,
                  u16* __restrict__ Qg, u16* __restrict__ Kg, u16* __restrict__ VTg) {
    __shared__ __align__(16) char smem[34816];
    char* ldsA = smem;            // [128][64] bf16 = 16 KB, chunk-swizzled
    char* ldsB = smem + 16384;    // [128][64] bf16 = 16 KB, chunk-swizzled
    u16*  ldsE = (u16*)smem;      // epilogue [128][136]

    // XCD-chunked bijective swizzle: 1536 = 8 XCDs x 192
    const int l = (blockIdx.x & 7) * 192 + (blockIdx.x >> 3);
    const int mode = l >> 9;
    const int bx = l & 511;
    const u16* W = (mode == 0) ? Wq : (mode == 1) ? Wk : Wv;
    const float* bias = (mode == 0) ? bq : (mode == 1) ? bk : bv;
    u16* Out = (mode == 0) ? Qg : (mode == 1) ? Kg : VTg;

    const int t = threadIdx.x;
    const int lane = t & 63, wave = t >> 6;
    const int lhi = lane >> 4, llo = lane & 15;
    const int wm = wave >> 1, wn = wave & 1;
    const int m0 = (bx >> 3) * 128;
    const int n0 = (bx & 7) * 128;

    // staging coords: linear LDS dest, pre-swizzled global source chunk
    const int srow = (t * 16) >> 7;                    // row within 32-row slab
    const int ssc = ((t * 16) >> 4) & 7;               // linear chunk
    v4f acc[4][4] = {};

    for (int k0 = 0; k0 < 1024; k0 += 64) {
        #pragma unroll
        for (int i = 0; i < 4; ++i) {
            int row = i * 32 + srow;
            int c = ssc ^ (row & 7);                   // inverse-swizzle source
            const char* wbaseA = ldsA + (i * 256 + wave * 64) * 16;
            const char* wbaseB = ldsB + (i * 256 + wave * 64) * 16;
            gload_lds16(X + (m0 + row) * 1024 + k0 + c * 8, wbaseA);
            gload_lds16(W + (n0 + row) * 1024 + k0 + c * 8, wbaseB);
        }
        __syncthreads();
        __builtin_amdgcn_s_setprio(1);
        #pragma unroll
        for (int s = 0; s < 2; ++s) {
            v8s af[4], bf[4];
            #pragma unroll
            for (int i = 0; i < 4; ++i) {
                int r = wm * 64 + i * 16 + llo;
                af[i] = *(const v8s*)(ldsA + r * 128 + (((lhi + 4 * s) ^ (r & 7)) << 4));
            }
            #pragma unroll
            for (int j = 0; j < 4; ++j) {
                int r = wn * 64 + j * 16 + llo;
                bf[j] = *(const v8s*)(ldsB + r * 128 + (((lhi + 4 * s) ^ (r & 7)) << 4));
            }
            #pragma unroll
            for (int i = 0; i < 4; ++i)
                #pragma unroll
                for (int j = 0; j < 4; ++j)
                    acc[i][j] = __builtin_amdgcn_mfma_f32_16x16x32_bf16(af[i], bf[j], acc[i][j], 0, 0, 0);
        }
        __builtin_amdgcn_s_setprio(0);
        __syncthreads();
    }

    // epilogue: bias (+scale) -> bf16 -> LDS -> coalesced global stores
    float bv_[4];
    #pragma unroll
    for (int j = 0; j < 4; ++j) bv_[j] = bias[n0 + wn * 64 + j * 16 + llo];
    const float scl = (mode == 0) ? 0.18033688011112042f : 1.0f;   // 0.125 * log2(e)

    #pragma unroll
    for (int i = 0; i < 4; ++i) {
        #pragma unroll
        for (int j = 0; j < 4; ++j) {
            #pragma unroll
            for (int r = 0; r < 4; ++r) {
                int ml = wm * 64 + i * 16 + lhi * 4 + r;
                int nl = wn * 64 + j * 16 + llo;
                float v = (acc[i][j][r] + bv_[j]) * scl;
                u16 hh = f2bf(v);
                if (mode == 2) ldsE[nl * 136 + ml] = hh;
                else           ldsE[ml * 136 + nl] = hh;
            }
        }
    }
    __syncthreads();

    const int row = t >> 1, half = t & 1;
    if (mode == 2) {
        int n = n0 + row, hh = n >> 6, dd = n & 63;
        int b = m0 >> 11, sbase = (m0 & 2047) + half * 64;
        u16* dst = Out + ((b * 16 + hh) * 64 + dd) * 2048 + sbase;
        #pragma unroll
        for (int j = 0; j < 8; ++j)
            *(v8s*)(dst + j * 8) = *(const v8s*)&ldsE[row * 136 + half * 64 + j * 8];
    } else {
        int m = m0 + row, b = m >> 11, s = m & 2047;
        int hh = (n0 + half * 64) >> 6;
        u16* dst = Out + ((b * 16 + hh) * 2048 + s) * 64;
        #pragma unroll
        for (int j = 0; j < 8; ++j)
            *(v8s*)(dst + j * 8) = *(const v8s*)&ldsE[row * 136 + half * 64 + j * 8];
    }
}

// ---------- causal flash attention (q2-ILP: 2 q-subtiles per wave, QBLK=128) ----------
// Per kv-tile each wave processes TWO independent q-subtiles (rows qw, qw+64):
// A's PV MFMAs overlap B's QKT/softmax; staging, barriers, K/V fetch per q-row
// halve vs QBLK=64. Single-buffered K/V (R14-proven), padded P (intra-wave,
// shared A/B sequentially), T13 defer-max, MFMA row-sum.
// Q [bh][s][d] (pre-scaled by 0.125*log2e), K [bh][s][d], VT [bh][d][s] bf16
// out fp32 [b][s][H]
__global__ __launch_bounds__(256, 4)
void flash_attn(const u16* __restrict__ Qg, const u16* __restrict__ Kg,
                const u16* __restrict__ VTg, const float* __restrict__ am,
                float* __restrict__ out) {
    __shared__ __align__(16) char smem[25088];
    char* ldsK = smem;                                   // [64][64] bf16 swizzled
    char* ldsV = smem + 8192;                            // VT [64][64] bf16 swizzled
    char* ldsP = smem + 16384 + (threadIdx.x >> 6) * 2176;  // per-wave P [16 q][68 kv] u16

    const int t = threadIdx.x;
    const int lane = t & 63, wave = t >> 6;
    const int lhi = lane >> 4, llo = lane & 15;
    const int bh = blockIdx.x;
    const int qi = 15 - blockIdx.y;        // heavy q-tiles dispatch first (LPT)
    const int b = bh >> 4, h = bh & 15;
    const int qwA = qi * 128 + wave * 16;  // subtile A rows
    const int qA = qwA + llo;
    const int qB = qA + 64;                // subtile B rows

    // Q fragments (B-operand layout: row n=llo, k = lhi*8 + 32s)
    v8s qfA[2], qfB[2];
    #pragma unroll
    for (int s = 0; s < 2; ++s) {
        qfA[s] = *(const v8s*)(Qg + (bh * 2048 + qA) * 64 + lhi * 8 + 32 * s);
        qfB[s] = *(const v8s*)(Qg + (bh * 2048 + qB) * 64 + lhi * 8 + 32 * s);
    }

    // all-ones bf16 A-fragment for the row-sum MFMA
    v8s ones;
    #pragma unroll
    for (int j = 0; j < 8; ++j) ones[j] = (short)0x3F80;

    const float rowpenA = am[b * 2048 + qA];   // >=1.0 means fully padded row
    const float rowpenB = am[b * 2048 + qB];

    // staging (pre-swizzled global source; 4 gload_lds per thread per tile)
    const int srow = (t * 16) >> 7, ssc = ((t * 16) >> 4) & 7;
    const int sc1 = ssc ^ (srow & 7), sc2 = ssc ^ ((srow + 32) & 7);
    #define STAGE(kj2) do {                                                        \
        const int kv0_ = (kj2) * 64;                                               \
        const char* wbK = ldsK + (wave * 64) * 16;                                 \
        const char* wbV = ldsV + (wave * 64) * 16;                                 \
        gload_lds16(Kg + (bh * 2048 + kv0_ + srow) * 64 + sc1 * 8, wbK);           \
        gload_lds16(VTg + (bh * 64 + srow) * 2048 + kv0_ + sc1 * 8, wbV);          \
        gload_lds16(Kg + (bh * 2048 + kv0_ + srow + 32) * 64 + sc2 * 8, wbK + 4096); \
        gload_lds16(VTg + (bh * 64 + srow + 32) * 2048 + kv0_ + sc2 * 8, wbV + 4096); \
    } while (0)

    float mrowA = -1e30f, mrowB = -1e30f;
    v4f lsumA = {}, lsumB = {};   // all 4 rows equal: sum_kv P[kv][q]
    v4f oA[4] = {}, oB[4] = {};   // O^T: d = dt*16 + lhi*4 + r, col q

    const int ntiles = 2 * qi + 2;
    for (int kj = 0; kj < ntiles; ++kj) {
        STAGE(kj);            // single buffer: prior readers done (barrier below)
        __syncthreads();      // drain + sync: tile kj fully in LDS
        const int kv0 = kj * 64;

        // ================= subtile A (q rows qwA..qwA+15) =================
        if (kj <= 2 * qi) {   // wave-uniform: A fully masked on the last tile
            const int ntA = (kj == 2 * qi) ? (wave + 1) : 4;
            v4f sacc[4] = {};
            __builtin_amdgcn_s_setprio(1);
            #pragma unroll
            for (int tt = 0; tt < 4; ++tt) {
                if (tt < ntA) {
                    #pragma unroll
                    for (int s = 0; s < 2; ++s) {
                        int row = tt * 16 + llo;
                        int c = lhi + 4 * s;
                        v8s kb = *(const v8s*)(ldsK + row * 128 + ((c ^ (row & 7)) << 4));
                        sacc[tt] = __builtin_amdgcn_mfma_f32_16x16x32_bf16(kb, qfA[s], sacc[tt], 0, 0, 0);
                    }
                }
            }
            __builtin_amdgcn_s_setprio(0);

            if (kj == 2 * qi) {           // diagonal tile for A
                #pragma unroll
                for (int tt = 0; tt < 4; ++tt)
                    #pragma unroll
                    for (int r = 0; r < 4; ++r) {
                        int kvg = kv0 + tt * 16 + lhi * 4 + r;
                        if (kvg > qA) sacc[tt][r] = -1e30f;
                    }
            }
            if (rowpenA >= 1.0f) {
                #pragma unroll
                for (int tt = 0; tt < 4; ++tt)
                    #pragma unroll
                    for (int r = 0; r < 4; ++r) sacc[tt][r] = -1e30f;
            }

            float m0_ = fmaxf(fmaxf(sacc[0][0], sacc[0][1]), sacc[0][2]);
            float m1_ = fmaxf(fmaxf(sacc[0][3], sacc[1][0]), sacc[1][1]);
            float m2_ = fmaxf(fmaxf(sacc[1][2], sacc[1][3]), sacc[2][0]);
            float m3_ = fmaxf(fmaxf(sacc[2][1], sacc[2][2]), sacc[2][3]);
            float m4_ = fmaxf(fmaxf(sacc[3][0], sacc[3][1]), fmaxf(sacc[3][2], sacc[3][3]));
            float lmx = fmaxf(fmaxf(fmaxf(m0_, m1_), fmaxf(m2_, m3_)), m4_);

            if (__any(lmx > mrowA + 8.0f)) {
                float mx = fmaxf(lmx, __shfl_xor(lmx, 16));
                mx = fmaxf(mx, __shfl_xor(mx, 32));
                const float mn = fmaxf(mrowA, mx);
                const float sc_o = ex2(mrowA - mn);
                mrowA = mn;
                #pragma unroll
                for (int r = 0; r < 4; ++r) lsumA[r] *= sc_o;
                #pragma unroll
                for (int dt = 0; dt < 4; ++dt)
                    #pragma unroll
                    for (int r = 0; r < 4; ++r) oA[dt][r] *= sc_o;
            }

            #pragma unroll
            for (int tt = 0; tt < 4; ++tt) {
                float p0 = ex2(sacc[tt][0] - mrowA);
                float p1 = ex2(sacc[tt][1] - mrowA);
                float p2 = ex2(sacc[tt][2] - mrowA);
                float p3 = ex2(sacc[tt][3] - mrowA);
                u32 w0 = cvt_pk_bf16(p0, p1);
                u32 w1 = cvt_pk_bf16(p2, p3);
                *(u64*)(ldsP + llo * 136 + tt * 32 + lhi * 8) = (u64)w0 | ((u64)w1 << 32);
            }

            __builtin_amdgcn_s_setprio(1);
            #pragma unroll
            for (int s = 0; s < 2; ++s) {
                u64 plo = *(const u64*)(ldsP + llo * 136 + lhi * 16 + s * 64);
                u64 phi = *(const u64*)(ldsP + llo * 136 + lhi * 16 + s * 64 + 8);
                v2u tmp; tmp.x = plo; tmp.y = phi;
                v8s pb = __builtin_bit_cast(v8s, tmp);
                lsumA = __builtin_amdgcn_mfma_f32_16x16x32_bf16(ones, pb, lsumA, 0, 0, 0);
                #pragma unroll
                for (int dt = 0; dt < 4; ++dt) {
                    int vrow = dt * 16 + llo;
                    v8s vb = *(const v8s*)(ldsV + vrow * 128 + (((lhi + 4 * s) ^ (vrow & 7)) << 4));
                    oA[dt] = __builtin_amdgcn_mfma_f32_16x16x32_bf16(vb, pb, oA[dt], 0, 0, 0);
                }
            }
            __builtin_amdgcn_s_setprio(0);
        }

        // ================= subtile B (q rows qwA+64..qwA+79) =================
        {
            const int ntB = (kj == 2 * qi + 1) ? (wave + 1) : 4;
            v4f sacc[4] = {};
            __builtin_amdgcn_s_setprio(1);
            #pragma unroll
            for (int tt = 0; tt < 4; ++tt) {
                if (tt < ntB) {
                    #pragma unroll
                    for (int s = 0; s < 2; ++s) {
                        int row = tt * 16 + llo;
                        int c = lhi + 4 * s;
                        v8s kb = *(const v8s*)(ldsK + row * 128 + ((c ^ (row & 7)) << 4));
                        sacc[tt] = __builtin_amdgcn_mfma_f32_16x16x32_bf16(kb, qfB[s], sacc[tt], 0, 0, 0);
                    }
                }
            }
            __builtin_amdgcn_s_setprio(0);

            if (kj == 2 * qi + 1) {       // diagonal tile for B (last tile)
                #pragma unroll
                for (int tt = 0; tt < 4; ++tt)
                    #pragma unroll
                    for (int r = 0; r < 4; ++r) {
                        int kvg = kv0 + tt * 16 + lhi * 4 + r;
                        if (kvg > qB) sacc[tt][r] = -1e30f;
                    }
            }
            if (rowpenB >= 1.0f) {
                #pragma unroll
                for (int tt = 0; tt < 4; ++tt)
                    #pragma unroll
                    for (int r = 0; r < 4; ++r) sacc[tt][r] = -1e30f;
            }

            float m0_ = fmaxf(fmaxf(sacc[0][0], sacc[0][1]), sacc[0][2]);
            float m1_ = fmaxf(fmaxf(sacc[0][3], sacc[1][0]), sacc[1][1]);
            float m2_ = fmaxf(fmaxf(sacc[1][2], sacc[1][3]), sacc[2][0]);
            float m3_ = fmaxf(fmaxf(sacc[2][1], sacc[2][2]), sacc[2][3]);
            float m4_ = fmaxf(fmaxf(sacc[3][0], sacc[3][1]), fmaxf(sacc[3][2], sacc[3][3]));
            float lmx = fmaxf(fmaxf(fmaxf(m0_, m1_), fmaxf(m2_, m3_)), m4_);

            if (__any(lmx > mrowB + 8.0f)) {
                float mx = fmaxf(lmx, __shfl_xor(lmx, 16));
                mx = fmaxf(mx, __shfl_xor(mx, 32));
                const float mn = fmaxf(mrowB, mx);
                const float sc_o = ex2(mrowB - mn);
                mrowB = mn;
                #pragma unroll
                for (int r = 0; r < 4; ++r) lsumB[r] *= sc_o;
                #pragma unroll
                for (int dt = 0; dt < 4; ++dt)
                    #pragma unroll
                    for (int r = 0; r < 4; ++r) oB[dt][r] *= sc_o;
            }

            #pragma unroll
            for (int tt = 0; tt < 4; ++tt) {
                float p0 = ex2(sacc[tt][0] - mrowB);
                float p1 = ex2(sacc[tt][1] - mrowB);
                float p2 = ex2(sacc[tt][2] - mrowB);
                float p3 = ex2(sacc[tt][3] - mrowB);
                u32 w0 = cvt_pk_bf16(p0, p1);
                u32 w1 = cvt_pk_bf16(p2, p3);
                *(u64*)(ldsP + llo * 136 + tt * 32 + lhi * 8) = (u64)w0 | ((u64)w1 << 32);
            }

            __builtin_amdgcn_s_setprio(1);
            #pragma unroll
            for (int s = 0; s < 2; ++s) {
                u64 plo = *(const u64*)(ldsP + llo * 136 + lhi * 16 + s * 64);
                u64 phi = *(const u64*)(ldsP + llo * 136 + lhi * 16 + s * 64 + 8);
                v2u tmp; tmp.x = plo; tmp.y = phi;
                v8s pb = __builtin_bit_cast(v8s, tmp);
                lsumB = __builtin_amdgcn_mfma_f32_16x16x32_bf16(ones, pb, lsumB, 0, 0, 0);
                #pragma unroll
                for (int dt = 0; dt < 4; ++dt) {
                    int vrow = dt * 16 + llo;
                    v8s vb = *(const v8s*)(ldsV + vrow * 128 + (((lhi + 4 * s) ^ (vrow & 7)) << 4));
                    oB[dt] = __builtin_amdgcn_mfma_f32_16x16x32_bf16(vb, pb, oB[dt], 0, 0, 0);
                }
            }
            __builtin_amdgcn_s_setprio(0);
        }
        __syncthreads();   // all readers of K/V/P done before next STAGE overwrites
    }

    // epilogue: out[b][q][h*64 + d] (lsum rows all equal -> no shuffle)
    const float invA = 1.0f / lsumA[0];
    const float invB = 1.0f / lsumB[0];
    float* dstA = out + (size_t)(b * 2048 + qA) * 1024 + h * 64 + lhi * 4;
    float* dstB = out + (size_t)(b * 2048 + qB) * 1024 + h * 64 + lhi * 4;
    #pragma unroll
    for (int dt = 0; dt < 4; ++dt) {
        float4 o;
        o.x = oA[dt][0] * invA;
        o.y = oA[dt][1] * invA;
        o.z = oA[dt][2] * invA;
        o.w = oA[dt][3] * invA;
        *(float4*)(dstA + dt * 16) = o;
        float4 p;
        p.x = oB[dt][0] * invB;
        p.y = oB[dt][1] * invB;
        p.z = oB[dt][2] * invB;
        p.w = oB[dt][3] * invB;
        *(float4*)(dstB + dt * 16) = p;
    }
}

// ---------- launch ----------
extern "C" void kernel_launch(void* const* d_in, const int* in_sizes, int n_in,
                              void* d_out, int out_size, void* d_ws, size_t ws_size,
                              hipStream_t stream) {
    const float* x  = (const float*)d_in[0];
    const float* Wq = (const float*)d_in[1];
    const float* bq = (const float*)d_in[2];
    const float* Wk = (const float*)d_in[3];
    const float* bk = (const float*)d_in[4];
    const float* Wv = (const float*)d_in[5];
    const float* bv = (const float*)d_in[6];
    const float* amask = (const float*)d_in[7];
    float* out = (float*)d_out;

    char* ws = (char*)d_ws;
    u16* xb  = (u16*)(ws);                         // 16 MB
    u16* Wqb = (u16*)(ws + 16777216);              // 2 MB
    u16* Wkb = (u16*)(ws + 16777216 + 2097152);
    u16* Wvb = (u16*)(ws + 16777216 + 2 * 2097152);
    u16* Qg  = (u16*)(ws + 23068672);              // 16 MB
    u16* Kg  = (u16*)(ws + 39845888);              // 16 MB
    u16* VTg = (u16*)(ws + 56623104);              // 16 MB

    cvt_all<<<11264, 256, 0, stream>>>(x, Wq, Wk, Wv, xb, Wqb, Wkb, Wvb);
    qkv_gemm_all<<<1536, 256, 0, stream>>>(xb, Wqb, Wkb, Wvb, bq, bk, bv, Qg, Kg, VTg);
    flash_attn<<<dim3(64, 16), 256, 0, stream>>>(Qg, Kg, VTg, amask, out);
}

// Round 19
// 148.213 us; speedup vs baseline: 1.0504x; 1.0504x over previous
//
#include <hip/hip_runtime.h>
#include <hip/hip_bf16.h>
#include <stdint.h>

typedef short v8s __attribute__((ext_vector_type(8)));
typedef float v4f __attribute__((ext_vector_type(4)));
typedef unsigned long long u64;
typedef unsigned short u16;
typedef unsigned int u32;
typedef u64 v2u __attribute__((ext_vector_type(2)));

// ---------- helpers ----------
__device__ __forceinline__ u16 f2bf(float f) {
    unsigned u = __builtin_bit_cast(unsigned, f);
    u += 0x7FFFu + ((u >> 16) & 1u);   // RNE
    return (u16)(u >> 16);
}

__device__ __forceinline__ u32 cvt_pk_bf16(float lo, float hi) {
    u32 r;
    asm("v_cvt_pk_bf16_f32 %0, %1, %2" : "=v"(r) : "v"(lo), "v"(hi));
    return r;
}

__device__ __forceinline__ float ex2(float x) {   // 2^x
    float r;
    asm("v_exp_f32 %0, %1" : "=v"(r) : "v"(x));
    return r;
}

__device__ __forceinline__ void gload_lds16(const void* g, const void* lds) {
    __builtin_amdgcn_global_load_lds(
        (const __attribute__((address_space(1))) unsigned int*)(unsigned long long)g,
        (__attribute__((address_space(3))) unsigned int*)(unsigned int)(unsigned long long)lds,
        16, 0, 0);
}

// ---------- fused fp32 -> bf16 conversion (x, Wq, Wk, Wv in one launch) ----------
__global__ __launch_bounds__(256) void cvt_all(const float* __restrict__ x,
                                               const float* __restrict__ wq,
                                               const float* __restrict__ wk,
                                               const float* __restrict__ wv,
                                               u16* __restrict__ xb, u16* __restrict__ wqb,
                                               u16* __restrict__ wkb, u16* __restrict__ wvb) {
    int i = blockIdx.x * 256 + threadIdx.x;   // v4 index over concatenated regions
    const float* in;
    u16* out;
    if (i < 2097152)      { in = x;  out = xb; }
    else if (i < 2359296) { in = wq; out = wqb; i -= 2097152; }
    else if (i < 2621440) { in = wk; out = wkb; i -= 2359296; }
    else                  { in = wv; out = wvb; i -= 2621440; }
    float4 v = ((const float4*)in)[i];
    ((ushort4*)out)[i] = make_ushort4(f2bf(v.x), f2bf(v.y), f2bf(v.z), f2bf(v.w));
}

// ---------- merged QKV projection GEMM (m97 structure + T2 swizzle + T1 XCD swizzle) ----------
// C[m][n] = sum_k X[m][k] * W[n][k] + bias[n]
// mode 0: Q -> [bh][s][d] bf16, scaled by 0.125*log2(e)
// mode 1: K -> [bh][s][d] bf16
// mode 2: V -> V^T [bh][d][s] bf16 (transposed via LDS)
__global__ __launch_bounds__(256, 4)
void qkv_gemm_all(const u16* __restrict__ X,
                  const u16* __restrict__ Wq, const u16* __restrict__ Wk, const u16* __restrict__ Wv,
                  const float* __restrict__ bq, const float* __restrict__ bk, const float* __restrict__ bv,
                  u16* __restrict__ Qg, u16* __restrict__ Kg, u16* __restrict__ VTg) {
    __shared__ __align__(16) char smem[34816];
    char* ldsA = smem;            // [128][64] bf16 = 16 KB, chunk-swizzled
    char* ldsB = smem + 16384;    // [128][64] bf16 = 16 KB, chunk-swizzled
    u16*  ldsE = (u16*)smem;      // epilogue [128][136]

    // XCD-chunked bijective swizzle: 1536 = 8 XCDs x 192
    const int l = (blockIdx.x & 7) * 192 + (blockIdx.x >> 3);
    const int mode = l >> 9;
    const int bx = l & 511;
    const u16* W = (mode == 0) ? Wq : (mode == 1) ? Wk : Wv;
    const float* bias = (mode == 0) ? bq : (mode == 1) ? bk : bv;
    u16* Out = (mode == 0) ? Qg : (mode == 1) ? Kg : VTg;

    const int t = threadIdx.x;
    const int lane = t & 63, wave = t >> 6;
    const int lhi = lane >> 4, llo = lane & 15;
    const int wm = wave >> 1, wn = wave & 1;
    const int m0 = (bx >> 3) * 128;
    const int n0 = (bx & 7) * 128;

    // staging coords: linear LDS dest, pre-swizzled global source chunk
    const int srow = (t * 16) >> 7;                    // row within 32-row slab
    const int ssc = ((t * 16) >> 4) & 7;               // linear chunk
    v4f acc[4][4] = {};

    for (int k0 = 0; k0 < 1024; k0 += 64) {
        #pragma unroll
        for (int i = 0; i < 4; ++i) {
            int row = i * 32 + srow;
            int c = ssc ^ (row & 7);                   // inverse-swizzle source
            const char* wbaseA = ldsA + (i * 256 + wave * 64) * 16;
            const char* wbaseB = ldsB + (i * 256 + wave * 64) * 16;
            gload_lds16(X + (m0 + row) * 1024 + k0 + c * 8, wbaseA);
            gload_lds16(W + (n0 + row) * 1024 + k0 + c * 8, wbaseB);
        }
        __syncthreads();
        __builtin_amdgcn_s_setprio(1);
        #pragma unroll
        for (int s = 0; s < 2; ++s) {
            v8s af[4], bf[4];
            #pragma unroll
            for (int i = 0; i < 4; ++i) {
                int r = wm * 64 + i * 16 + llo;
                af[i] = *(const v8s*)(ldsA + r * 128 + (((lhi + 4 * s) ^ (r & 7)) << 4));
            }
            #pragma unroll
            for (int j = 0; j < 4; ++j) {
                int r = wn * 64 + j * 16 + llo;
                bf[j] = *(const v8s*)(ldsB + r * 128 + (((lhi + 4 * s) ^ (r & 7)) << 4));
            }
            #pragma unroll
            for (int i = 0; i < 4; ++i)
                #pragma unroll
                for (int j = 0; j < 4; ++j)
                    acc[i][j] = __builtin_amdgcn_mfma_f32_16x16x32_bf16(af[i], bf[j], acc[i][j], 0, 0, 0);
        }
        __builtin_amdgcn_s_setprio(0);
        __syncthreads();
    }

    // epilogue: bias (+scale) -> bf16 -> LDS -> coalesced global stores
    float bv_[4];
    #pragma unroll
    for (int j = 0; j < 4; ++j) bv_[j] = bias[n0 + wn * 64 + j * 16 + llo];
    const float scl = (mode == 0) ? 0.18033688011112042f : 1.0f;   // 0.125 * log2(e)

    #pragma unroll
    for (int i = 0; i < 4; ++i) {
        #pragma unroll
        for (int j = 0; j < 4; ++j) {
            #pragma unroll
            for (int r = 0; r < 4; ++r) {
                int ml = wm * 64 + i * 16 + lhi * 4 + r;
                int nl = wn * 64 + j * 16 + llo;
                float v = (acc[i][j][r] + bv_[j]) * scl;
                u16 hh = f2bf(v);
                if (mode == 2) ldsE[nl * 136 + ml] = hh;
                else           ldsE[ml * 136 + nl] = hh;
            }
        }
    }
    __syncthreads();

    const int row = t >> 1, half = t & 1;
    if (mode == 2) {
        int n = n0 + row, hh = n >> 6, dd = n & 63;
        int b = m0 >> 11, sbase = (m0 & 2047) + half * 64;
        u16* dst = Out + ((b * 16 + hh) * 64 + dd) * 2048 + sbase;
        #pragma unroll
        for (int j = 0; j < 8; ++j)
            *(v8s*)(dst + j * 8) = *(const v8s*)&ldsE[row * 136 + half * 64 + j * 8];
    } else {
        int m = m0 + row, b = m >> 11, s = m & 2047;
        int hh = (n0 + half * 64) >> 6;
        u16* dst = Out + ((b * 16 + hh) * 2048 + s) * 64;
        #pragma unroll
        for (int j = 0; j < 8; ++j)
            *(v8s*)(dst + j * 8) = *(const v8s*)&ldsE[row * 136 + half * 64 + j * 8];
    }
}

// ---------- causal flash attention (R14: single-buffered K/V, 6 blocks/CU) ----------
// swapped QK^T, in-register softmax, T13 defer-max, MFMA row-sum, padded P.
// Q [bh][s][d] (pre-scaled by 0.125*log2e), K [bh][s][d], VT [bh][d][s] bf16
// out fp32 [b][s][H]
__global__ __launch_bounds__(256, 6)
void flash_attn(const u16* __restrict__ Qg, const u16* __restrict__ Kg,
                const u16* __restrict__ VTg, const float* __restrict__ am,
                float* __restrict__ out) {
    __shared__ __align__(16) char smem[25088];
    char* ldsK = smem;                                   // [64][64] bf16 swizzled
    char* ldsV = smem + 8192;                            // VT [64][64] bf16 swizzled
    char* ldsP = smem + 16384 + (threadIdx.x >> 6) * 2176;  // per-wave P [16 q][68 kv] u16

    const int t = threadIdx.x;
    const int lane = t & 63, wave = t >> 6;
    const int lhi = lane >> 4, llo = lane & 15;
    const int bh = blockIdx.x;
    const int qi = 31 - blockIdx.y;        // heavy tiles dispatch first (LPT)
    const int b = bh >> 4, h = bh & 15;
    const int qw = qi * 64 + wave * 16;
    const int q = qw + llo;                // this lane's q row

    // Q fragment (B-operand layout: row n=llo, k = lhi*8 + 32s)
    v8s qf[2];
    #pragma unroll
    for (int s = 0; s < 2; ++s)
        qf[s] = *(const v8s*)(Qg + (bh * 2048 + q) * 64 + lhi * 8 + 32 * s);

    // all-ones bf16 A-fragment for the row-sum MFMA
    v8s ones;
    #pragma unroll
    for (int j = 0; j < 8; ++j) ones[j] = (short)0x3F80;

    const float rowpen = am[b * 2048 + q];   // >=1.0 means fully padded row

    // staging (pre-swizzled global source; 4 gload_lds per thread per tile)
    const int srow = (t * 16) >> 7, ssc = ((t * 16) >> 4) & 7;
    const int sc1 = ssc ^ (srow & 7), sc2 = ssc ^ ((srow + 32) & 7);
    #define STAGE(kj2) do {                                                        \
        const int kv0_ = (kj2) * 64;                                               \
        const char* wbK = ldsK + (wave * 64) * 16;                                 \
        const char* wbV = ldsV + (wave * 64) * 16;                                 \
        gload_lds16(Kg + (bh * 2048 + kv0_ + srow) * 64 + sc1 * 8, wbK);           \
        gload_lds16(VTg + (bh * 64 + srow) * 2048 + kv0_ + sc1 * 8, wbV);          \
        gload_lds16(Kg + (bh * 2048 + kv0_ + srow + 32) * 64 + sc2 * 8, wbK + 4096); \
        gload_lds16(VTg + (bh * 64 + srow + 32) * 2048 + kv0_ + sc2 * 8, wbV + 4096); \
    } while (0)

    float mrow = -1e30f;
    v4f lsum_acc = {};   // all 4 rows equal: sum_kv P[kv][q=llo]
    v4f o_acc[4] = {};   // O^T: d = dt*16 + lhi*4 + r, col q = llo

    for (int kj = 0; kj <= qi; ++kj) {
        STAGE(kj);            // single buffer: prior readers done (barrier below)
        __syncthreads();      // drain + sync: tile kj fully in LDS
        const int kv0 = kj * 64;

        // S^T[kv][q] = K . Q^T : A = K rows (kv), B = Q rows (q)
        const int nt4 = (kj == qi) ? (wave + 1) : 4;   // skip fully-masked diag subtiles
        v4f sacc[4] = {};
        __builtin_amdgcn_s_setprio(1);
        #pragma unroll
        for (int tt = 0; tt < 4; ++tt) {
            if (tt < nt4) {
                #pragma unroll
                for (int s = 0; s < 2; ++s) {
                    int row = tt * 16 + llo;
                    int c = lhi + 4 * s;
                    v8s kb = *(const v8s*)(ldsK + row * 128 + ((c ^ (row & 7)) << 4));
                    sacc[tt] = __builtin_amdgcn_mfma_f32_16x16x32_bf16(kb, qf[s], sacc[tt], 0, 0, 0);
                }
            }
        }
        __builtin_amdgcn_s_setprio(0);

        // causal mask on diagonal tile (covers skipped subtiles too: sacc=0 -> -1e30)
        if (kj == qi) {
            #pragma unroll
            for (int tt = 0; tt < 4; ++tt)
                #pragma unroll
                for (int r = 0; r < 4; ++r) {
                    int kvg = kv0 + tt * 16 + lhi * 4 + r;
                    if (kvg > q) sacc[tt][r] = -1e30f;
                }
        }
        if (rowpen >= 1.0f) {
            #pragma unroll
            for (int tt = 0; tt < 4; ++tt)
                #pragma unroll
                for (int r = 0; r < 4; ++r) sacc[tt][r] = -1e30f;
        }

        // T13 defer-max (max3-friendly triples): cross-lane reduce only on growth
        float m0_ = fmaxf(fmaxf(sacc[0][0], sacc[0][1]), sacc[0][2]);
        float m1_ = fmaxf(fmaxf(sacc[0][3], sacc[1][0]), sacc[1][1]);
        float m2_ = fmaxf(fmaxf(sacc[1][2], sacc[1][3]), sacc[2][0]);
        float m3_ = fmaxf(fmaxf(sacc[2][1], sacc[2][2]), sacc[2][3]);
        float m4_ = fmaxf(fmaxf(sacc[3][0], sacc[3][1]), fmaxf(sacc[3][2], sacc[3][3]));
        float lmx = fmaxf(fmaxf(fmaxf(m0_, m1_), fmaxf(m2_, m3_)), m4_);

        if (__any(lmx > mrow + 8.0f)) {       // rare after a q-tile's first kv-tile
            float mx = fmaxf(lmx, __shfl_xor(lmx, 16));
            mx = fmaxf(mx, __shfl_xor(mx, 32));
            const float mn = fmaxf(mrow, mx);
            const float sc_o = ex2(mrow - mn);
            mrow = mn;
            #pragma unroll
            for (int r = 0; r < 4; ++r) lsum_acc[r] *= sc_o;
            #pragma unroll
            for (int dt = 0; dt < 4; ++dt)
                #pragma unroll
                for (int r = 0; r < 4; ++r) o_acc[dt][r] *= sc_o;
        }

        #pragma unroll
        for (int tt = 0; tt < 4; ++tt) {
            float p0 = ex2(sacc[tt][0] - mrow);
            float p1 = ex2(sacc[tt][1] - mrow);
            float p2 = ex2(sacc[tt][2] - mrow);
            float p3 = ex2(sacc[tt][3] - mrow);
            u32 w0 = cvt_pk_bf16(p0, p1);
            u32 w1 = cvt_pk_bf16(p2, p3);
            // P[q=llo][kv = tt*16 + lhi*4 + 0..3]  (136B rows: conflict-free)
            *(u64*)(ldsP + llo * 136 + tt * 32 + lhi * 8) = (u64)w0 | ((u64)w1 << 32);
        }

        // PV: O^T[d][q] += V^T[d][kv] * P^T[kv][q] ; row-sum on the matrix pipe
        __builtin_amdgcn_s_setprio(1);
        #pragma unroll
        for (int s = 0; s < 2; ++s) {
            u64 plo = *(const u64*)(ldsP + llo * 136 + lhi * 16 + s * 64);
            u64 phi = *(const u64*)(ldsP + llo * 136 + lhi * 16 + s * 64 + 8);
            v2u tmp; tmp.x = plo; tmp.y = phi;
            v8s pb = __builtin_bit_cast(v8s, tmp);
            lsum_acc = __builtin_amdgcn_mfma_f32_16x16x32_bf16(ones, pb, lsum_acc, 0, 0, 0);
            #pragma unroll
            for (int dt = 0; dt < 4; ++dt) {
                int vrow = dt * 16 + llo;
                v8s vb = *(const v8s*)(ldsV + vrow * 128 + (((lhi + 4 * s) ^ (vrow & 7)) << 4));
                o_acc[dt] = __builtin_amdgcn_mfma_f32_16x16x32_bf16(vb, pb, o_acc[dt], 0, 0, 0);
            }
        }
        __builtin_amdgcn_s_setprio(0);
        __syncthreads();   // all readers of K/V/P done before next STAGE overwrites
    }

    // epilogue: out[b][q][h*64 + d] (lsum_acc rows all equal -> no shuffle)
    const float inv = 1.0f / lsum_acc[0];
    float* dst = out + (size_t)(b * 2048 + q) * 1024 + h * 64 + lhi * 4;
    #pragma unroll
    for (int dt = 0; dt < 4; ++dt) {
        float4 o;
        o.x = o_acc[dt][0] * inv;
        o.y = o_acc[dt][1] * inv;
        o.z = o_acc[dt][2] * inv;
        o.w = o_acc[dt][3] * inv;
        *(float4*)(dst + dt * 16) = o;
    }
}

// ---------- launch ----------
extern "C" void kernel_launch(void* const* d_in, const int* in_sizes, int n_in,
                              void* d_out, int out_size, void* d_ws, size_t ws_size,
                              hipStream_t stream) {
    const float* x  = (const float*)d_in[0];
    const float* Wq = (const float*)d_in[1];
    const float* bq = (const float*)d_in[2];
    const float* Wk = (const float*)d_in[3];
    const float* bk = (const float*)d_in[4];
    const float* Wv = (const float*)d_in[5];
    const float* bv = (const float*)d_in[6];
    const float* amask = (const float*)d_in[7];
    float* out = (float*)d_out;

    char* ws = (char*)d_ws;
    u16* xb  = (u16*)(ws);                         // 16 MB
    u16* Wqb = (u16*)(ws + 16777216);              // 2 MB
    u16* Wkb = (u16*)(ws + 16777216 + 2097152);
    u16* Wvb = (u16*)(ws + 16777216 + 2 * 2097152);
    u16* Qg  = (u16*)(ws + 23068672);              // 16 MB
    u16* Kg  = (u16*)(ws + 39845888);              // 16 MB
    u16* VTg = (u16*)(ws + 56623104);              // 16 MB

    cvt_all<<<11264, 256, 0, stream>>>(x, Wq, Wk, Wv, xb, Wqb, Wkb, Wvb);
    qkv_gemm_all<<<1536, 256, 0, stream>>>(xb, Wqb, Wkb, Wvb, bq, bk, bv, Qg, Kg, VTg);
    flash_attn<<<dim3(64, 32), 256, 0, stream>>>(Qg, Kg, VTg, amask, out);
}